// Round 2
// baseline (30.262 us; speedup 1.0000x reference)
//
#include <hip/hip_runtime.h>
#include <math.h>

#define N_PTS 131072
#define UNITS 256
#define BLOCK 256
#define GRID  (N_PTS / BLOCK)   // 512 blocks, one thread per point

// Fused kernel: per-point RBF sums + block partials + last-block final reduce.
//
// Closed form: phi = exp(-0.5*s), s = (x-cx)^2+(y-cy)^2
//   u_pred = sum phi*w
//   sh = u + 2*lap + biharm = sum phi*w*(s^2 - 6s + 5)
// Expansion: t = c*s = c*(x^2+y^2) + c*K_j + A_j*x + B_j*y,
//   c = -0.5*log2(e), A_j = -2c*cx, B_j = -2c*cy, K_j = cx^2+cy^2
//   phi = exp2(t);  s = t/c, so s^2-6s+5 = fma(t, fma(ic2, t, m6ic), 5)
__global__ __launch_bounds__(BLOCK) void rbf_pinn_fused(
    const float* __restrict__ x, const float* __restrict__ y,
    const float* __restrict__ u, const float* __restrict__ centers,
    const float* __restrict__ W, const float* __restrict__ eps,
    const float* __restrict__ delta, const float* __restrict__ gam,
    const int* __restrict__ iters, float* __restrict__ partial,
    unsigned int* __restrict__ counter, float* __restrict__ out)
{
    __shared__ float4 s_coef[UNITS];
    const int t = threadIdx.x;
    const float c = -0.72134752044448170368f;  // -0.5 * log2(e)

    // Per-block prologue: pack per-center coefficients (UNITS == BLOCK).
    {
        const float cx = centers[2 * t + 0];
        const float cy = centers[2 * t + 1];
        const float w  = W[t];
        const float A  = -2.f * c * cx;
        const float B  = -2.f * c * cy;
        const float D  = c * fmaf(cx, cx, cy * cy);
        s_coef[t] = make_float4(A, B, D, w);
    }
    __syncthreads();

    const int i = blockIdx.x * BLOCK + t;
    const float xi = x[i];
    const float yi = y[i];
    const float ui = u[i];
    const float tb = c * fmaf(xi, xi, yi * yi);   // c*(x^2+y^2)

    const float ic2  = 1.9218120556728056f;       // (1/c)^2
    const float m6ic = 8.3187661667193446f;       // -6*(1/c)

    float up = 0.f;   // u_pred
    float sh = 0.f;   // u + 2*laplace + biharmonic

    #pragma unroll 8
    for (int j = 0; j < UNITS; ++j) {
        const float4 cf = s_coef[j];              // one ds_read_b128, broadcast
        const float tt = fmaf(cf.x, xi, fmaf(cf.y, yi, tb + cf.z));
        const float e  = __builtin_amdgcn_exp2f(tt);
        const float ew = e * cf.w;
        up += ew;
        const float u1   = fmaf(ic2, tt, m6ic);
        const float poly = fmaf(tt, u1, 5.f);     // s^2 - 6s + 5
        sh = fmaf(ew, poly, sh);
    }

    const int   it   = iters[0];
    const float epsv = eps[0];
    const float dl   = delta[0];
    const float gm   = gam[0];
    float c2, c3;
    if (it < 10000)      { c2 = 0.0f; c3 = 0.0f; }
    else if (it < 20000) { c2 = 0.3f; c3 = 0.0f; }
    else if (it < 30000) { c2 = 0.7f; c3 = 0.3f; }
    else                 { c2 = 1.0f; c3 = 1.0f; }

    const float up2 = up * up;
    const float res = epsv * up - c2 * dl * up2 - c3 * gm * up2 * up - sh;
    const float d   = up - ui;

    float a0 = d * d;
    float a1 = ui * ui;
    float a2 = res * res;

    #pragma unroll
    for (int o = 32; o > 0; o >>= 1) {
        a0 += __shfl_down(a0, o);
        a1 += __shfl_down(a1, o);
        a2 += __shfl_down(a2, o);
    }
    __shared__ float s_r[3][BLOCK / 64];
    const int lane = t & 63;
    const int wv   = t >> 6;
    if (lane == 0) { s_r[0][wv] = a0; s_r[1][wv] = a1; s_r[2][wv] = a2; }
    __syncthreads();

    __shared__ bool s_last;
    if (t == 0) {
        float r0 = 0.f, r1 = 0.f, r2 = 0.f;
        #pragma unroll
        for (int w2 = 0; w2 < BLOCK / 64; ++w2) {
            r0 += s_r[0][w2]; r1 += s_r[1][w2]; r2 += s_r[2][w2];
        }
        partial[0 * GRID + blockIdx.x] = r0;
        partial[1 * GRID + blockIdx.x] = r1;
        partial[2 * GRID + blockIdx.x] = r2;
        __threadfence();                          // publish partials (device scope)
        const unsigned old = atomicAdd(counter, 1u);
        s_last = (old == GRID - 1);
    }
    __syncthreads();
    if (!s_last) return;

    // Last block: final reduction (fixed read order -> deterministic).
    __threadfence();
    float b0 = 0.f, b1 = 0.f, b2 = 0.f;
    #pragma unroll
    for (int k = t; k < GRID; k += BLOCK) {
        b0 += partial[0 * GRID + k];
        b1 += partial[1 * GRID + k];
        b2 += partial[2 * GRID + k];
    }
    #pragma unroll
    for (int o = 32; o > 0; o >>= 1) {
        b0 += __shfl_down(b0, o);
        b1 += __shfl_down(b1, o);
        b2 += __shfl_down(b2, o);
    }
    if (lane == 0) { s_r[0][wv] = b0; s_r[1][wv] = b1; s_r[2][wv] = b2; }
    __syncthreads();
    if (t == 0) {
        float S0 = 0.f, S1 = 0.f, S2 = 0.f;
        #pragma unroll
        for (int w2 = 0; w2 < BLOCK / 64; ++w2) {
            S0 += s_r[0][w2]; S1 += s_r[1][w2]; S2 += s_r[2][w2];
        }
        const float loss_u   = S0 / S1;
        const float loss_pde = S2 / (float)N_PTS;
        float cw;
        if (it < 10000)      cw = 0.1f;
        else if (it < 20000) cw = 0.3f;
        else if (it < 30000) cw = 0.6f;
        else                 cw = 1.0f;
        const float e  = epsv;
        const float p0 = fmaxf(0.f, e - 0.8f);
        const float p1 = fmaxf(0.f, 0.2f - e);
        const float eps_bp = p0 * p0 + p1 * p1;
        out[0] = 0.1f * loss_u + cw * loss_pde + 0.01f * eps_bp;
        out[1] = loss_u;
        out[2] = loss_pde;
    }
}

extern "C" void kernel_launch(void* const* d_in, const int* in_sizes, int n_in,
                              void* d_out, int out_size, void* d_ws, size_t ws_size,
                              hipStream_t stream) {
    const float* x       = (const float*)d_in[0];
    const float* y       = (const float*)d_in[1];
    const float* u       = (const float*)d_in[2];
    const float* centers = (const float*)d_in[3];
    const float* W       = (const float*)d_in[4];
    const float* eps     = (const float*)d_in[5];
    const float* delta   = (const float*)d_in[6];
    const float* gam     = (const float*)d_in[7];
    const int*   iters   = (const int*)d_in[8];
    float* out = (float*)d_out;

    float* partial = (float*)d_ws;                          // 3*512 floats
    unsigned int* counter = (unsigned int*)((char*)d_ws + 8192);

    hipMemsetAsync(counter, 0, sizeof(unsigned int), stream);
    rbf_pinn_fused<<<GRID, BLOCK, 0, stream>>>(x, y, u, centers, W, eps, delta,
                                               gam, iters, partial, counter, out);
}